// Round 1
// baseline (326.456 us; speedup 1.0000x reference)
//
#include <hip/hip_runtime.h>
#include <hip/hip_bf16.h>
#include <stdint.h>

// Problem constants: B=2, L=512, D=1024, INNER=32, PAIR=128
// out[b,i,j,p] = sum_e q[b,j,e]*(k[b,i,e]*Wp[p,e] + Wd[p,e]) + (b_o[p] - sum_e k[b,i,e]*Wd[p,e])
//   => per (b,i): GEMM with M=p (128), N=j (512), K=e (32) via mfma_f32_16x16x32_bf16,
//      operand-swapped so D's m-dim = p -> each lane's 4 acc regs are p-contiguous
//      -> direct 16B nontemporal stores, no LDS transpose.

typedef __attribute__((ext_vector_type(8))) short short8;
typedef __attribute__((ext_vector_type(4))) float floatx4;

__device__ __forceinline__ unsigned short f2bf(float f) {
    union { float f; unsigned int u; } v; v.f = f;
    return (unsigned short)((v.u + 0x7FFFu + ((v.u >> 16) & 1u)) >> 16); // RNE
}

__device__ __forceinline__ floatx4 fmadd4(float s, floatx4 w, floatx4 a) {
    a.x += s * w.x; a.y += s * w.y; a.z += s * w.z; a.w += s * w.w; return a;
}

// ---------------- k0: transpose weights (k1's operands only) ----------------
// Wt[d][o]  = W_proj[o][d]   (1024 x 64)   -- k1 projection
// Wdt[e][p] = W_o[p][32+e]   (32 x 128)    -- k1 c0 phase
__global__ __launch_bounds__(256) void k0_transpose(
    const float* __restrict__ Wproj, const float* __restrict__ Wo,
    float* __restrict__ Wt, float* __restrict__ Wdt)
{
    int g = blockIdx.x * 256 + threadIdx.x;
    if (g < 65536) {
        int o = g >> 10, d = g & 1023;
        Wt[d * 64 + o] = Wproj[g];
    } else {
        int h = g - 65536;           // 0..4095
        int e = h >> 7, p = h & 127;
        Wdt[h] = Wo[p * 64 + 32 + e];
    }
}

// ---------------- k1: LayerNorm + projection + c0 ----------------
// 256 blocks x 256 threads, 4 rows per block. Projection uses float4 Wt loads.
__global__ __launch_bounds__(256) void k1_ln_proj(
    const float* __restrict__ x, const float* __restrict__ gamma, const float* __restrict__ beta,
    const float* __restrict__ Wt, const float* __restrict__ b_proj,
    const float* __restrict__ Wdt, const float* __restrict__ b_o,
    unsigned short* __restrict__ Qbf, float* __restrict__ Kf, float* __restrict__ C0)
{
    __shared__ __attribute__((aligned(16))) float s_sh[4][1024];
    __shared__ __attribute__((aligned(16))) float part[4][16][68];  // [row][chunk][o], o-dim padded
    __shared__ float k_sh[4][32];

    const int t = threadIdx.x;
    const int w = t >> 6;        // wave id = local row for LN phase
    const int lane = t & 63;
    const int row = blockIdx.x * 4 + w;

    // --- LayerNorm of this wave's row ---
    const float* xr = x + (size_t)row * 1024;
    floatx4 xv[4];
    float sum = 0.f, sq = 0.f;
#pragma unroll
    for (int c = 0; c < 4; ++c) {
        xv[c] = *(const floatx4*)(xr + (c * 64 + lane) * 4);
        sum += xv[c].x + xv[c].y + xv[c].z + xv[c].w;
        sq  += xv[c].x * xv[c].x + xv[c].y * xv[c].y + xv[c].z * xv[c].z + xv[c].w * xv[c].w;
    }
#pragma unroll
    for (int m = 1; m < 64; m <<= 1) {
        sum += __shfl_xor(sum, m, 64);
        sq  += __shfl_xor(sq,  m, 64);
    }
    const float mu   = sum * (1.f / 1024.f);
    const float var  = sq * (1.f / 1024.f) - mu * mu;
    const float rsig = rsqrtf(var + 1e-5f);
#pragma unroll
    for (int c = 0; c < 4; ++c) {
        int d = (c * 64 + lane) * 4;
        floatx4 g4 = *(const floatx4*)(gamma + d);
        floatx4 b4 = *(const floatx4*)(beta + d);
        floatx4 s4;
        s4.x = (xv[c].x - mu) * rsig * g4.x + b4.x;
        s4.y = (xv[c].y - mu) * rsig * g4.y + b4.y;
        s4.z = (xv[c].z - mu) * rsig * g4.z + b4.z;
        s4.w = (xv[c].w - mu) * rsig * g4.w + b4.w;
        *(floatx4*)(&s_sh[w][d]) = s4;
    }
    __syncthreads();

    // --- projection: thread t -> outputs 4*(t&15)..+3, d-chunk (t>>4) of 64 ---
    {
        const int o4 = t & 15;
        const int ch = t >> 4;
        const floatx4* Wt4 = (const floatx4*)Wt;
        floatx4 a0 = {0.f, 0.f, 0.f, 0.f}, a1 = a0, a2 = a0, a3 = a0;
        const int dbase = ch * 64;
#pragma unroll 8
        for (int dd = 0; dd < 64; ++dd) {
            const int d = dbase + dd;
            floatx4 w4 = Wt4[d * 16 + o4];   // 16B coalesced, L2-resident
            a0 = fmadd4(s_sh[0][d], w4, a0);
            a1 = fmadd4(s_sh[1][d], w4, a1);
            a2 = fmadd4(s_sh[2][d], w4, a2);
            a3 = fmadd4(s_sh[3][d], w4, a3);
        }
        *(floatx4*)&part[0][ch][o4 * 4] = a0;
        *(floatx4*)&part[1][ch][o4 * 4] = a1;
        *(floatx4*)&part[2][ch][o4 * 4] = a2;
        *(floatx4*)&part[3][ch][o4 * 4] = a3;
    }
    __syncthreads();

    // --- combine partials: thread t -> (r = t>>6, o = t&63) ---
    {
        const int r = t >> 6, oo = t & 63;
        float v = b_proj[oo];
#pragma unroll
        for (int c = 0; c < 16; ++c) v += part[r][c][oo];
        const int rowr = blockIdx.x * 4 + r;
        if (oo < 32) {
            Qbf[rowr * 32 + oo] = f2bf(v);     // q in bf16 (MFMA B operand)
        } else {
            Kf[rowr * 32 + (oo - 32)] = v;     // k in fp32
            k_sh[r][oo - 32] = v;
        }
    }
    __syncthreads();

    // --- c0[row][p] = b_o[p] - sum_e k[row][e]*Wd[p][e]  (exact fp32) ---
    {
        const int p = t & 127;
        const int r0 = t >> 7;  // 0 or 1
#pragma unroll
        for (int rr = 0; rr < 2; ++rr) {
            const int r = r0 * 2 + rr;
            float a = 0.f;
#pragma unroll 8
            for (int e = 0; e < 32; ++e) a += k_sh[r][e] * Wdt[e * 128 + p];
            C0[(size_t)(blockIdx.x * 4 + r) * 128 + p] = b_o[p] - a;
        }
    }
}

// ---------------- k2: pairwise GEMM, operand-swapped, zero-LDS epilogue ----------------
// 1024 blocks x 256 threads: one block per (b,i). G[p][e] bf16 in LDS (built once),
// fragments via 8x ds_read_b128; 4 waves x 8 j-tiles; D layout (m=p, n=j) makes each
// lane's 4 acc regs p-contiguous -> direct 16B nontemporal stores (16x64B chunks/instr).
__global__ __launch_bounds__(256, 4) void k2_pair(
    const unsigned short* __restrict__ Qbf, const float* __restrict__ Kf,
    const float* __restrict__ C0, const float* __restrict__ Wo,
    float* __restrict__ out)
{
    __shared__ __attribute__((aligned(16))) unsigned short G2[128 * 40]; // [p][e], rows 32->40 (80B, 16B-aligned)

    const int t  = threadIdx.x;
    const int bi = blockIdx.x;        // b*512 + i
    const int b  = bi >> 9;

    // Build G2[p][e] = bf16( k_i[e]*Wo[p][e] + Wo[p][32+e] ); Wo slices are contiguous in input layout.
    {
        const int p  = t >> 1;
        const int eh = (t & 1) * 16;
        const float* kp = Kf + (size_t)bi * 32 + eh;   // broadcast, L1-served
        const float* wp = Wo + p * 64 + eh;            // 64B contiguous per thread
        unsigned short g[16];
#pragma unroll
        for (int c = 0; c < 4; ++c) {
            floatx4 kc  = *(const floatx4*)(kp + c * 4);
            floatx4 wpc = *(const floatx4*)(wp + c * 4);
            floatx4 wdc = *(const floatx4*)(wp + 32 + c * 4);
            g[c * 4 + 0] = f2bf(kc.x * wpc.x + wdc.x);
            g[c * 4 + 1] = f2bf(kc.y * wpc.y + wdc.y);
            g[c * 4 + 2] = f2bf(kc.z * wpc.z + wdc.z);
            g[c * 4 + 3] = f2bf(kc.w * wpc.w + wdc.w);
        }
        short8 lo, hi;
#pragma unroll
        for (int u = 0; u < 8; ++u) { lo[u] = (short)g[u]; hi[u] = (short)g[8 + u]; }
        *(short8*)(&G2[p * 40 + eh])     = lo;
        *(short8*)(&G2[p * 40 + eh + 8]) = hi;
    }
    __syncthreads();

    const int wave = t >> 6, lane = t & 63;
    const int col = lane & 15, quad = lane >> 4;

    // A-operand (G^T): A[m][k] = G[k][pt*16+m], lane m=col, k=quad*8+u -> one b128 per pt
    short8 gfrag[8];
#pragma unroll
    for (int pt = 0; pt < 8; ++pt)
        gfrag[pt] = *(const short8*)(&G2[(pt * 16 + col) * 40 + quad * 8]);

    // C-in: c0[p] at p = pt*16 + quad*4 + r  (r = acc reg index)
    floatx4 cv[8];
#pragma unroll
    for (int pt = 0; pt < 8; ++pt)
        cv[pt] = *(const floatx4*)(C0 + (size_t)bi * 128 + pt * 16 + quad * 4);

    float* outb = out + (size_t)bi * (512 * 128) + (size_t)col * 128 + quad * 4;
    const unsigned short* qb = Qbf + ((size_t)b * 512 + col) * 32 + quad * 8;

    for (int l = 0; l < 8; ++l) {
        const int j0 = (wave * 8 + l) * 16;
        // B-operand (Q): B[k][n] = Q[j0+n][k], lane n=col, k=quad*8+u -> one 16B global load (1KB/wave, L2-hit)
        const short8 afrag = *(const short8*)(qb + (size_t)j0 * 32);
        float* orow = outb + (size_t)j0 * 128;
#pragma unroll
        for (int pt = 0; pt < 8; ++pt) {
            floatx4 acc = __builtin_amdgcn_mfma_f32_16x16x32_bf16(gfrag[pt], afrag, cv[pt], 0, 0, 0);
            __builtin_nontemporal_store(acc, (floatx4*)(orow + pt * 16));
        }
    }
}

extern "C" void kernel_launch(void* const* d_in, const int* in_sizes, int n_in,
                              void* d_out, int out_size, void* d_ws, size_t ws_size,
                              hipStream_t stream) {
    const float* x     = (const float*)d_in[0];  // (2,512,1024)
    const float* gamma = (const float*)d_in[1];  // (1024)
    const float* beta  = (const float*)d_in[2];  // (1024)
    const float* Wproj = (const float*)d_in[3];  // (64,1024)
    const float* bproj = (const float*)d_in[4];  // (64)
    const float* Wo    = (const float*)d_in[5];  // (128,64)
    const float* bo    = (const float*)d_in[6];  // (128)
    float* out = (float*)d_out;                  // (2,512,512,128) fp32

    float* ws = (float*)d_ws;
    float* Wt  = ws;                    // 65536 floats (1024x64)
    float* Wdt = ws + 65536;            // 4096 floats  (32x128)
    float* Kf  = ws + 69632;            // 32768 floats (1024x32)
    float* C0  = ws + 102400;           // 131072 floats (1024x128)
    unsigned short* Qbf = (unsigned short*)(ws + 233472); // 32768 ushorts (1024x32)

    hipLaunchKernelGGL(k0_transpose, dim3(272), dim3(256), 0, stream,
                       Wproj, Wo, Wt, Wdt);
    hipLaunchKernelGGL(k1_ln_proj, dim3(256), dim3(256), 0, stream,
                       x, gamma, beta, Wt, bproj, Wdt, bo, Qbf, Kf, C0);
    hipLaunchKernelGGL(k2_pair, dim3(1024), dim3(256), 0, stream,
                       Qbf, Kf, C0, Wo, out);
}

// Round 2
// 325.251 us; speedup vs baseline: 1.0037x; 1.0037x over previous
//
#include <hip/hip_runtime.h>
#include <hip/hip_bf16.h>
#include <stdint.h>

// Problem constants: B=2, L=512, D=1024, INNER=32, PAIR=128
// out[b,i,j,p] = sum_e q[b,j,e]*(k[b,i,e]*Wp[p,e] + Wd[p,e]) + (b_o[p] - sum_e k[b,i,e]*Wd[p,e])
//   => per (b,i): GEMM with M=p (128), N=j (512), K=e (32) via mfma_f32_16x16x32_bf16,
//      operand-swapped so D's m-dim = p -> each lane's 4 acc regs are p-contiguous
//      -> direct 16B nontemporal stores. G precomputed per (b,i) in k1 -> k2 has no LDS,
//      no barriers, ~95 VGPR, all 1024 blocks co-resident.

typedef __attribute__((ext_vector_type(8))) short short8;
typedef __attribute__((ext_vector_type(4))) float floatx4;

__device__ __forceinline__ unsigned short f2bf(float f) {
    union { float f; unsigned int u; } v; v.f = f;
    return (unsigned short)((v.u + 0x7FFFu + ((v.u >> 16) & 1u)) >> 16); // RNE
}

__device__ __forceinline__ floatx4 fmadd4(float s, floatx4 w, floatx4 a) {
    a.x += s * w.x; a.y += s * w.y; a.z += s * w.z; a.w += s * w.w; return a;
}

// ---------------- k0: transpose weights (k1's operands only) ----------------
// Wt[d][o]  = W_proj[o][d]   (1024 x 64)   -- k1 projection
// Wdt[e][p] = W_o[p][32+e]   (32 x 128)    -- k1 c0 phase
__global__ __launch_bounds__(256) void k0_transpose(
    const float* __restrict__ Wproj, const float* __restrict__ Wo,
    float* __restrict__ Wt, float* __restrict__ Wdt)
{
    int g = blockIdx.x * 256 + threadIdx.x;
    if (g < 65536) {
        int o = g >> 10, d = g & 1023;
        Wt[d * 64 + o] = Wproj[g];
    } else {
        int h = g - 65536;           // 0..4095
        int e = h >> 7, p = h & 127;
        Wdt[h] = Wo[p * 64 + 32 + e];
    }
}

// ---------------- k1: LayerNorm + projection + c0 + G build ----------------
// 256 blocks x 256 threads, 4 rows per block. Projection uses float4 Wt loads.
// Also materializes Gall[row][p][e] = bf16(k[row][e]*Wp[p][e] + Wd[p][e]) (8 MB total).
__global__ __launch_bounds__(256) void k1_ln_proj(
    const float* __restrict__ x, const float* __restrict__ gamma, const float* __restrict__ beta,
    const float* __restrict__ Wt, const float* __restrict__ b_proj,
    const float* __restrict__ Wdt, const float* __restrict__ b_o,
    const float* __restrict__ Wo,
    unsigned short* __restrict__ Qbf, float* __restrict__ C0,
    unsigned short* __restrict__ Gall)
{
    __shared__ __attribute__((aligned(16))) float s_sh[4][1024];
    __shared__ __attribute__((aligned(16))) float part[4][16][68];  // [row][chunk][o], o-dim padded
    __shared__ float k_sh[4][32];

    const int t = threadIdx.x;
    const int w = t >> 6;        // wave id = local row for LN phase
    const int lane = t & 63;
    const int row = blockIdx.x * 4 + w;

    // --- LayerNorm of this wave's row ---
    const float* xr = x + (size_t)row * 1024;
    floatx4 xv[4];
    float sum = 0.f, sq = 0.f;
#pragma unroll
    for (int c = 0; c < 4; ++c) {
        xv[c] = *(const floatx4*)(xr + (c * 64 + lane) * 4);
        sum += xv[c].x + xv[c].y + xv[c].z + xv[c].w;
        sq  += xv[c].x * xv[c].x + xv[c].y * xv[c].y + xv[c].z * xv[c].z + xv[c].w * xv[c].w;
    }
#pragma unroll
    for (int m = 1; m < 64; m <<= 1) {
        sum += __shfl_xor(sum, m, 64);
        sq  += __shfl_xor(sq,  m, 64);
    }
    const float mu   = sum * (1.f / 1024.f);
    const float var  = sq * (1.f / 1024.f) - mu * mu;
    const float rsig = rsqrtf(var + 1e-5f);
#pragma unroll
    for (int c = 0; c < 4; ++c) {
        int d = (c * 64 + lane) * 4;
        floatx4 g4 = *(const floatx4*)(gamma + d);
        floatx4 b4 = *(const floatx4*)(beta + d);
        floatx4 s4;
        s4.x = (xv[c].x - mu) * rsig * g4.x + b4.x;
        s4.y = (xv[c].y - mu) * rsig * g4.y + b4.y;
        s4.z = (xv[c].z - mu) * rsig * g4.z + b4.z;
        s4.w = (xv[c].w - mu) * rsig * g4.w + b4.w;
        *(floatx4*)(&s_sh[w][d]) = s4;
    }
    __syncthreads();

    // --- projection: thread t -> outputs 4*(t&15)..+3, d-chunk (t>>4) of 64 ---
    {
        const int o4 = t & 15;
        const int ch = t >> 4;
        const floatx4* Wt4 = (const floatx4*)Wt;
        floatx4 a0 = {0.f, 0.f, 0.f, 0.f}, a1 = a0, a2 = a0, a3 = a0;
        const int dbase = ch * 64;
#pragma unroll 8
        for (int dd = 0; dd < 64; ++dd) {
            const int d = dbase + dd;
            floatx4 w4 = Wt4[d * 16 + o4];   // 16B coalesced, L2-resident
            a0 = fmadd4(s_sh[0][d], w4, a0);
            a1 = fmadd4(s_sh[1][d], w4, a1);
            a2 = fmadd4(s_sh[2][d], w4, a2);
            a3 = fmadd4(s_sh[3][d], w4, a3);
        }
        *(floatx4*)&part[0][ch][o4 * 4] = a0;
        *(floatx4*)&part[1][ch][o4 * 4] = a1;
        *(floatx4*)&part[2][ch][o4 * 4] = a2;
        *(floatx4*)&part[3][ch][o4 * 4] = a3;
    }
    __syncthreads();

    // --- combine partials: thread t -> (r = t>>6, o = t&63) ---
    {
        const int r = t >> 6, oo = t & 63;
        float v = b_proj[oo];
#pragma unroll
        for (int c = 0; c < 16; ++c) v += part[r][c][oo];
        const int rowr = blockIdx.x * 4 + r;
        if (oo < 32) {
            Qbf[rowr * 32 + oo] = f2bf(v);     // q in bf16 (MFMA B operand)
        } else {
            k_sh[r][oo - 32] = v;              // k stays on-chip
        }
    }
    __syncthreads();

    // --- c0[row][p] = b_o[p] - sum_e k[row][e]*Wd[p][e]  (exact fp32) ---
    {
        const int p = t & 127;
        const int r0 = t >> 7;  // 0 or 1
#pragma unroll
        for (int rr = 0; rr < 2; ++rr) {
            const int r = r0 * 2 + rr;
            float a = 0.f;
#pragma unroll 8
            for (int e = 0; e < 32; ++e) a += k_sh[r][e] * Wdt[e * 128 + p];
            C0[(size_t)(blockIdx.x * 4 + r) * 128 + p] = b_o[p] - a;
        }
    }

    // --- Gall[row][p][e] = bf16(k[row][e]*Wp[p][e] + Wd[p][e]), rows of 32 shorts (64B) ---
    {
        const int p  = t >> 1;
        const int eh = (t & 1) * 16;
        const float* wp = Wo + p * 64 + eh;
        floatx4 wpc[4], wdc[4];
#pragma unroll
        for (int c = 0; c < 4; ++c) {
            wpc[c] = *(const floatx4*)(wp + c * 4);        // Wp[p][eh+4c .. +3]
            wdc[c] = *(const floatx4*)(wp + 32 + c * 4);   // Wd[p][eh+4c .. +3]
        }
#pragma unroll
        for (int r = 0; r < 4; ++r) {
            unsigned short g[16];
#pragma unroll
            for (int c = 0; c < 4; ++c) {
#pragma unroll
                for (int u = 0; u < 4; ++u) {
                    float kv = k_sh[r][eh + c * 4 + u];
                    g[c * 4 + u] = f2bf(kv * wpc[c][u] + wdc[c][u]);
                }
            }
            short8 lo, hi;
#pragma unroll
            for (int u = 0; u < 8; ++u) { lo[u] = (short)g[u]; hi[u] = (short)g[8 + u]; }
            unsigned short* gr = Gall + (size_t)(blockIdx.x * 4 + r) * 4096 + p * 32 + eh;
            *(short8*)(gr)     = lo;
            *(short8*)(gr + 8) = hi;
        }
    }
}

// ---------------- k2: pairwise GEMM, zero-LDS, zero-barrier ----------------
// 1024 blocks x 256 threads: one block per (b,i), all co-resident (4/CU).
// Per wave: 8 resident G-fragments + 8 C0 vectors; loop over 8 j-tiles:
// 1 coalesced 1KB Q load, 8 MFMA, 8 direct 16B nontemporal stores (full 64B lines).
__global__ __launch_bounds__(256, 4) void k2_pair(
    const unsigned short* __restrict__ Qbf, const unsigned short* __restrict__ Gall,
    const float* __restrict__ C0, float* __restrict__ out)
{
    const int t  = threadIdx.x;
    const int bi = blockIdx.x;        // b*512 + i
    const int b  = bi >> 9;
    const int wave = t >> 6, lane = t & 63;
    const int col = lane & 15, quad = lane >> 4;

    // A-operand (G^T): A[m][k] = G[pt*16+col][quad*8+u] -> contiguous 1KB wave-load per pt
    const unsigned short* gb = Gall + (size_t)bi * 4096 + (size_t)col * 32 + quad * 8;
    short8 gfrag[8];
#pragma unroll
    for (int pt = 0; pt < 8; ++pt)
        gfrag[pt] = *(const short8*)(gb + pt * 512);

    // C-in: c0[p] at p = pt*16 + quad*4 + r (r = acc reg index); broadcast across col
    floatx4 cv[8];
#pragma unroll
    for (int pt = 0; pt < 8; ++pt)
        cv[pt] = *(const floatx4*)(C0 + (size_t)bi * 128 + pt * 16 + quad * 4);

    // B-operand (Q): B[k][n] = Q[j0+col][quad*8+u] -> contiguous 1KB wave-load per j-tile
    const unsigned short* qp = Qbf + ((size_t)b * 512 + wave * 128 + col) * 32 + quad * 8;
    float* orow = out + (size_t)bi * (512 * 128) + (size_t)(wave * 128 + col) * 128 + quad * 4;

    short8 a_cur = *(const short8*)qp;
#pragma unroll 1
    for (int l = 0; l < 8; ++l) {
        short8 a_nxt = a_cur;
        if (l < 7) a_nxt = *(const short8*)(qp + (size_t)(l + 1) * 512);
#pragma unroll
        for (int pt = 0; pt < 8; ++pt) {
            floatx4 acc = __builtin_amdgcn_mfma_f32_16x16x32_bf16(gfrag[pt], a_cur, cv[pt], 0, 0, 0);
            __builtin_nontemporal_store(acc, (floatx4*)(orow + pt * 16));
        }
        orow += 16 * 128;
        a_cur = a_nxt;
    }
}

extern "C" void kernel_launch(void* const* d_in, const int* in_sizes, int n_in,
                              void* d_out, int out_size, void* d_ws, size_t ws_size,
                              hipStream_t stream) {
    const float* x     = (const float*)d_in[0];  // (2,512,1024)
    const float* gamma = (const float*)d_in[1];  // (1024)
    const float* beta  = (const float*)d_in[2];  // (1024)
    const float* Wproj = (const float*)d_in[3];  // (64,1024)
    const float* bproj = (const float*)d_in[4];  // (64)
    const float* Wo    = (const float*)d_in[5];  // (128,64)
    const float* bo    = (const float*)d_in[6];  // (128)
    float* out = (float*)d_out;                  // (2,512,512,128) fp32

    float* ws = (float*)d_ws;
    float* Wt  = ws;                    // 65536 floats (1024x64)
    float* Wdt = ws + 65536;            // 4096 floats  (32x128)
    float* C0  = ws + 69632;            // 131072 floats (1024x128)
    unsigned short* Qbf  = (unsigned short*)(ws + 200704); // 32768 ushorts (1024x32)
    unsigned short* Gall = (unsigned short*)(ws + 217088); // 4194304 ushorts (1024x128x32)

    hipLaunchKernelGGL(k0_transpose, dim3(272), dim3(256), 0, stream,
                       Wproj, Wo, Wt, Wdt);
    hipLaunchKernelGGL(k1_ln_proj, dim3(256), dim3(256), 0, stream,
                       x, gamma, beta, Wt, bproj, Wdt, bo, Wo, Qbf, C0, Gall);
    hipLaunchKernelGGL(k2_pair, dim3(1024), dim3(256), 0, stream,
                       Qbf, Gall, C0, out);
}

// Round 3
// 294.809 us; speedup vs baseline: 1.1073x; 1.1033x over previous
//
#include <hip/hip_runtime.h>
#include <hip/hip_bf16.h>
#include <stdint.h>

// Problem constants: B=2, L=512, D=1024, INNER=32, PAIR=128
// out[b,i,j,p] = sum_e q[b,j,e]*(k[b,i,e]*Wp[p,e] + Wd[p,e]) + (b_o[p] - sum_e k[b,i,e]*Wd[p,e])
//   => per (b,i): GEMM with M=p (128), N=j (512), K=e (32) via mfma_f32_16x16x32_bf16,
//      operand-swapped so D's m-dim = p -> each lane's 4 acc regs are p-contiguous
//      -> direct 16B stores. G precomputed per (b,i) in k1 -> k2 has no LDS, no barriers.
// R3 change: PLAIN stores (no nontemporal). Theory: nt (no-allocate) bypasses L2
// write-aggregation and caps streaming writes at ~2-2.6 TB/s; plain write-allocate
// stores merge to full dirty lines in L2 and evict at full HBM efficiency (the
// poison-fill kernel proves 6.3 TB/s with plain stores at 10% occupancy).

typedef __attribute__((ext_vector_type(8))) short short8;
typedef __attribute__((ext_vector_type(4))) float floatx4;

__device__ __forceinline__ unsigned short f2bf(float f) {
    union { float f; unsigned int u; } v; v.f = f;
    return (unsigned short)((v.u + 0x7FFFu + ((v.u >> 16) & 1u)) >> 16); // RNE
}

__device__ __forceinline__ floatx4 fmadd4(float s, floatx4 w, floatx4 a) {
    a.x += s * w.x; a.y += s * w.y; a.z += s * w.z; a.w += s * w.w; return a;
}

// ---------------- k0: transpose weights (k1's operands only) ----------------
// Wt[d][o]  = W_proj[o][d]   (1024 x 64)   -- k1 projection
// Wdt[e][p] = W_o[p][32+e]   (32 x 128)    -- k1 c0 phase
__global__ __launch_bounds__(256) void k0_transpose(
    const float* __restrict__ Wproj, const float* __restrict__ Wo,
    float* __restrict__ Wt, float* __restrict__ Wdt)
{
    int g = blockIdx.x * 256 + threadIdx.x;
    if (g < 65536) {
        int o = g >> 10, d = g & 1023;
        Wt[d * 64 + o] = Wproj[g];
    } else {
        int h = g - 65536;           // 0..4095
        int e = h >> 7, p = h & 127;
        Wdt[h] = Wo[p * 64 + 32 + e];
    }
}

// ---------------- k1: LayerNorm + projection + c0 + G build ----------------
// 256 blocks x 256 threads, 4 rows per block. Projection uses float4 Wt loads.
// Also materializes Gall[row][p][e] = bf16(k[row][e]*Wp[p][e] + Wd[p][e]) (8 MB total).
__global__ __launch_bounds__(256) void k1_ln_proj(
    const float* __restrict__ x, const float* __restrict__ gamma, const float* __restrict__ beta,
    const float* __restrict__ Wt, const float* __restrict__ b_proj,
    const float* __restrict__ Wdt, const float* __restrict__ b_o,
    const float* __restrict__ Wo,
    unsigned short* __restrict__ Qbf, float* __restrict__ C0,
    unsigned short* __restrict__ Gall)
{
    __shared__ __attribute__((aligned(16))) float s_sh[4][1024];
    __shared__ __attribute__((aligned(16))) float part[4][16][68];  // [row][chunk][o], o-dim padded
    __shared__ float k_sh[4][32];

    const int t = threadIdx.x;
    const int w = t >> 6;        // wave id = local row for LN phase
    const int lane = t & 63;
    const int row = blockIdx.x * 4 + w;

    // --- LayerNorm of this wave's row ---
    const float* xr = x + (size_t)row * 1024;
    floatx4 xv[4];
    float sum = 0.f, sq = 0.f;
#pragma unroll
    for (int c = 0; c < 4; ++c) {
        xv[c] = *(const floatx4*)(xr + (c * 64 + lane) * 4);
        sum += xv[c].x + xv[c].y + xv[c].z + xv[c].w;
        sq  += xv[c].x * xv[c].x + xv[c].y * xv[c].y + xv[c].z * xv[c].z + xv[c].w * xv[c].w;
    }
#pragma unroll
    for (int m = 1; m < 64; m <<= 1) {
        sum += __shfl_xor(sum, m, 64);
        sq  += __shfl_xor(sq,  m, 64);
    }
    const float mu   = sum * (1.f / 1024.f);
    const float var  = sq * (1.f / 1024.f) - mu * mu;
    const float rsig = rsqrtf(var + 1e-5f);
#pragma unroll
    for (int c = 0; c < 4; ++c) {
        int d = (c * 64 + lane) * 4;
        floatx4 g4 = *(const floatx4*)(gamma + d);
        floatx4 b4 = *(const floatx4*)(beta + d);
        floatx4 s4;
        s4.x = (xv[c].x - mu) * rsig * g4.x + b4.x;
        s4.y = (xv[c].y - mu) * rsig * g4.y + b4.y;
        s4.z = (xv[c].z - mu) * rsig * g4.z + b4.z;
        s4.w = (xv[c].w - mu) * rsig * g4.w + b4.w;
        *(floatx4*)(&s_sh[w][d]) = s4;
    }
    __syncthreads();

    // --- projection: thread t -> outputs 4*(t&15)..+3, d-chunk (t>>4) of 64 ---
    {
        const int o4 = t & 15;
        const int ch = t >> 4;
        const floatx4* Wt4 = (const floatx4*)Wt;
        floatx4 a0 = {0.f, 0.f, 0.f, 0.f}, a1 = a0, a2 = a0, a3 = a0;
        const int dbase = ch * 64;
#pragma unroll 8
        for (int dd = 0; dd < 64; ++dd) {
            const int d = dbase + dd;
            floatx4 w4 = Wt4[d * 16 + o4];   // 16B coalesced, L2-resident
            a0 = fmadd4(s_sh[0][d], w4, a0);
            a1 = fmadd4(s_sh[1][d], w4, a1);
            a2 = fmadd4(s_sh[2][d], w4, a2);
            a3 = fmadd4(s_sh[3][d], w4, a3);
        }
        *(floatx4*)&part[0][ch][o4 * 4] = a0;
        *(floatx4*)&part[1][ch][o4 * 4] = a1;
        *(floatx4*)&part[2][ch][o4 * 4] = a2;
        *(floatx4*)&part[3][ch][o4 * 4] = a3;
    }
    __syncthreads();

    // --- combine partials: thread t -> (r = t>>6, o = t&63) ---
    {
        const int r = t >> 6, oo = t & 63;
        float v = b_proj[oo];
#pragma unroll
        for (int c = 0; c < 16; ++c) v += part[r][c][oo];
        const int rowr = blockIdx.x * 4 + r;
        if (oo < 32) {
            Qbf[rowr * 32 + oo] = f2bf(v);     // q in bf16 (MFMA B operand)
        } else {
            k_sh[r][oo - 32] = v;              // k stays on-chip
        }
    }
    __syncthreads();

    // --- c0[row][p] = b_o[p] - sum_e k[row][e]*Wd[p][e]  (exact fp32) ---
    {
        const int p = t & 127;
        const int r0 = t >> 7;  // 0 or 1
#pragma unroll
        for (int rr = 0; rr < 2; ++rr) {
            const int r = r0 * 2 + rr;
            float a = 0.f;
#pragma unroll 8
            for (int e = 0; e < 32; ++e) a += k_sh[r][e] * Wdt[e * 128 + p];
            C0[(size_t)(blockIdx.x * 4 + r) * 128 + p] = b_o[p] - a;
        }
    }

    // --- Gall[row][p][e] = bf16(k[row][e]*Wp[p][e] + Wd[p][e]), rows of 32 shorts (64B) ---
    {
        const int p  = t >> 1;
        const int eh = (t & 1) * 16;
        const float* wp = Wo + p * 64 + eh;
        floatx4 wpc[4], wdc[4];
#pragma unroll
        for (int c = 0; c < 4; ++c) {
            wpc[c] = *(const floatx4*)(wp + c * 4);        // Wp[p][eh+4c .. +3]
            wdc[c] = *(const floatx4*)(wp + 32 + c * 4);   // Wd[p][eh+4c .. +3]
        }
#pragma unroll
        for (int r = 0; r < 4; ++r) {
            unsigned short g[16];
#pragma unroll
            for (int c = 0; c < 4; ++c) {
#pragma unroll
                for (int u = 0; u < 4; ++u) {
                    float kv = k_sh[r][eh + c * 4 + u];
                    g[c * 4 + u] = f2bf(kv * wpc[c][u] + wdc[c][u]);
                }
            }
            short8 lo, hi;
#pragma unroll
            for (int u = 0; u < 8; ++u) { lo[u] = (short)g[u]; hi[u] = (short)g[8 + u]; }
            unsigned short* gr = Gall + (size_t)(blockIdx.x * 4 + r) * 4096 + p * 32 + eh;
            *(short8*)(gr)     = lo;
            *(short8*)(gr + 8) = hi;
        }
    }
}

// ---------------- k2: pairwise GEMM, zero-LDS, zero-barrier, PLAIN stores ----------------
// 1024 blocks x 256 threads: one block per (b,i), all co-resident (4/CU).
// Per wave: 8 resident G-fragments + 8 C0 vectors; loop over 8 j-tiles:
// 1 coalesced 1KB Q load, 8 MFMA, 8 direct 16B stores. The 8 pt-stores of a row land
// within ~10 cycles -> L2 lines fill completely -> full-line dirty evictions to HBM.
__global__ __launch_bounds__(256, 4) void k2_pair(
    const unsigned short* __restrict__ Qbf, const unsigned short* __restrict__ Gall,
    const float* __restrict__ C0, float* __restrict__ out)
{
    const int t  = threadIdx.x;
    const int bi = blockIdx.x;        // b*512 + i
    const int b  = bi >> 9;
    const int wave = t >> 6, lane = t & 63;
    const int col = lane & 15, quad = lane >> 4;

    // A-operand (G^T): A[m][k] = G[pt*16+col][quad*8+u] -> contiguous 1KB wave-load per pt
    const unsigned short* gb = Gall + (size_t)bi * 4096 + (size_t)col * 32 + quad * 8;
    short8 gfrag[8];
#pragma unroll
    for (int pt = 0; pt < 8; ++pt)
        gfrag[pt] = *(const short8*)(gb + pt * 512);

    // C-in: c0[p] at p = pt*16 + quad*4 + r (r = acc reg index); broadcast across col
    floatx4 cv[8];
#pragma unroll
    for (int pt = 0; pt < 8; ++pt)
        cv[pt] = *(const floatx4*)(C0 + (size_t)bi * 128 + pt * 16 + quad * 4);

    // B-operand (Q): B[k][n] = Q[j0+col][quad*8+u] -> contiguous 1KB wave-load per j-tile
    const unsigned short* qp = Qbf + ((size_t)b * 512 + wave * 128 + col) * 32 + quad * 8;
    float* orow = out + (size_t)bi * (512 * 128) + (size_t)(wave * 128 + col) * 128 + quad * 4;

    short8 a_cur = *(const short8*)qp;
#pragma unroll 1
    for (int l = 0; l < 8; ++l) {
        short8 a_nxt = a_cur;
        if (l < 7) a_nxt = *(const short8*)(qp + (size_t)(l + 1) * 512);
#pragma unroll
        for (int pt = 0; pt < 8; ++pt) {
            floatx4 acc = __builtin_amdgcn_mfma_f32_16x16x32_bf16(gfrag[pt], a_cur, cv[pt], 0, 0, 0);
            *(floatx4*)(orow + pt * 16) = acc;   // plain store: L2 write-allocate + merge
        }
        orow += 16 * 128;
        a_cur = a_nxt;
    }
}

extern "C" void kernel_launch(void* const* d_in, const int* in_sizes, int n_in,
                              void* d_out, int out_size, void* d_ws, size_t ws_size,
                              hipStream_t stream) {
    const float* x     = (const float*)d_in[0];  // (2,512,1024)
    const float* gamma = (const float*)d_in[1];  // (1024)
    const float* beta  = (const float*)d_in[2];  // (1024)
    const float* Wproj = (const float*)d_in[3];  // (64,1024)
    const float* bproj = (const float*)d_in[4];  // (64)
    const float* Wo    = (const float*)d_in[5];  // (128,64)
    const float* bo    = (const float*)d_in[6];  // (128)
    float* out = (float*)d_out;                  // (2,512,512,128) fp32

    float* ws = (float*)d_ws;
    float* Wt  = ws;                    // 65536 floats (1024x64)
    float* Wdt = ws + 65536;            // 4096 floats  (32x128)
    float* C0  = ws + 69632;            // 131072 floats (1024x128)
    unsigned short* Qbf  = (unsigned short*)(ws + 200704); // 32768 ushorts (1024x32)
    unsigned short* Gall = (unsigned short*)(ws + 217088); // 4194304 ushorts (1024x128x32)

    hipLaunchKernelGGL(k0_transpose, dim3(272), dim3(256), 0, stream,
                       Wproj, Wo, Wt, Wdt);
    hipLaunchKernelGGL(k1_ln_proj, dim3(256), dim3(256), 0, stream,
                       x, gamma, beta, Wt, bproj, Wdt, bo, Wo, Qbf, C0, Gall);
    hipLaunchKernelGGL(k2_pair, dim3(1024), dim3(256), 0, stream,
                       Qbf, Gall, C0, out);
}

// Round 4
// 290.863 us; speedup vs baseline: 1.1224x; 1.0136x over previous
//
#include <hip/hip_runtime.h>
#include <hip/hip_bf16.h>
#include <stdint.h>

// Problem constants: B=2, L=512, D=1024, INNER=32, PAIR=128
// out[b,i,j,p] = sum_e q[b,j,e]*(k[b,i,e]*Wp[p,e] + Wd[p,e]) + (b_o[p] - sum_e k[b,i,e]*Wd[p,e])
//   => per (b,i): GEMM with M=p (128), N=j (512), K=e (32) via mfma_f32_16x16x32_bf16.
// R4: A/B matrix completed. nt was -30us (R3), scatter is the other -30/-40us penalty:
// direct stores put 16 rows x 64B per instruction (partial lines -> RFO / burst loss).
// Fix: per-wave LDS transpose tile (rotated chunk placement for bank uniformity), then
// PLAIN contiguous 1KB stores -- each wave emits a sequential 64KB write stream, same
// shape as the 6.3 TB/s fill kernel. No cross-wave barriers; Gall still precomputed.

typedef __attribute__((ext_vector_type(8))) short short8;
typedef __attribute__((ext_vector_type(4))) float floatx4;

__device__ __forceinline__ unsigned short f2bf(float f) {
    union { float f; unsigned int u; } v; v.f = f;
    return (unsigned short)((v.u + 0x7FFFu + ((v.u >> 16) & 1u)) >> 16); // RNE
}

__device__ __forceinline__ floatx4 fmadd4(float s, floatx4 w, floatx4 a) {
    a.x += s * w.x; a.y += s * w.y; a.z += s * w.z; a.w += s * w.w; return a;
}

// ---------------- k0: transpose weights (k1's operands only) ----------------
__global__ __launch_bounds__(256) void k0_transpose(
    const float* __restrict__ Wproj, const float* __restrict__ Wo,
    float* __restrict__ Wt, float* __restrict__ Wdt)
{
    int g = blockIdx.x * 256 + threadIdx.x;
    if (g < 65536) {
        int o = g >> 10, d = g & 1023;
        Wt[d * 64 + o] = Wproj[g];
    } else {
        int h = g - 65536;           // 0..4095
        int e = h >> 7, p = h & 127;
        Wdt[h] = Wo[p * 64 + 32 + e];
    }
}

// ---------------- k1: LayerNorm + projection + c0 + G build ----------------
__global__ __launch_bounds__(256) void k1_ln_proj(
    const float* __restrict__ x, const float* __restrict__ gamma, const float* __restrict__ beta,
    const float* __restrict__ Wt, const float* __restrict__ b_proj,
    const float* __restrict__ Wdt, const float* __restrict__ b_o,
    const float* __restrict__ Wo,
    unsigned short* __restrict__ Qbf, float* __restrict__ C0,
    unsigned short* __restrict__ Gall)
{
    __shared__ __attribute__((aligned(16))) float s_sh[4][1024];
    __shared__ __attribute__((aligned(16))) float part[4][16][68];  // [row][chunk][o], o-dim padded
    __shared__ float k_sh[4][32];

    const int t = threadIdx.x;
    const int w = t >> 6;        // wave id = local row for LN phase
    const int lane = t & 63;
    const int row = blockIdx.x * 4 + w;

    // --- LayerNorm of this wave's row ---
    const float* xr = x + (size_t)row * 1024;
    floatx4 xv[4];
    float sum = 0.f, sq = 0.f;
#pragma unroll
    for (int c = 0; c < 4; ++c) {
        xv[c] = *(const floatx4*)(xr + (c * 64 + lane) * 4);
        sum += xv[c].x + xv[c].y + xv[c].z + xv[c].w;
        sq  += xv[c].x * xv[c].x + xv[c].y * xv[c].y + xv[c].z * xv[c].z + xv[c].w * xv[c].w;
    }
#pragma unroll
    for (int m = 1; m < 64; m <<= 1) {
        sum += __shfl_xor(sum, m, 64);
        sq  += __shfl_xor(sq,  m, 64);
    }
    const float mu   = sum * (1.f / 1024.f);
    const float var  = sq * (1.f / 1024.f) - mu * mu;
    const float rsig = rsqrtf(var + 1e-5f);
#pragma unroll
    for (int c = 0; c < 4; ++c) {
        int d = (c * 64 + lane) * 4;
        floatx4 g4 = *(const floatx4*)(gamma + d);
        floatx4 b4 = *(const floatx4*)(beta + d);
        floatx4 s4;
        s4.x = (xv[c].x - mu) * rsig * g4.x + b4.x;
        s4.y = (xv[c].y - mu) * rsig * g4.y + b4.y;
        s4.z = (xv[c].z - mu) * rsig * g4.z + b4.z;
        s4.w = (xv[c].w - mu) * rsig * g4.w + b4.w;
        *(floatx4*)(&s_sh[w][d]) = s4;
    }
    __syncthreads();

    // --- projection: thread t -> outputs 4*(t&15)..+3, d-chunk (t>>4) of 64 ---
    {
        const int o4 = t & 15;
        const int ch = t >> 4;
        const floatx4* Wt4 = (const floatx4*)Wt;
        floatx4 a0 = {0.f, 0.f, 0.f, 0.f}, a1 = a0, a2 = a0, a3 = a0;
        const int dbase = ch * 64;
#pragma unroll 8
        for (int dd = 0; dd < 64; ++dd) {
            const int d = dbase + dd;
            floatx4 w4 = Wt4[d * 16 + o4];   // 16B coalesced, L2-resident
            a0 = fmadd4(s_sh[0][d], w4, a0);
            a1 = fmadd4(s_sh[1][d], w4, a1);
            a2 = fmadd4(s_sh[2][d], w4, a2);
            a3 = fmadd4(s_sh[3][d], w4, a3);
        }
        *(floatx4*)&part[0][ch][o4 * 4] = a0;
        *(floatx4*)&part[1][ch][o4 * 4] = a1;
        *(floatx4*)&part[2][ch][o4 * 4] = a2;
        *(floatx4*)&part[3][ch][o4 * 4] = a3;
    }
    __syncthreads();

    // --- combine partials: thread t -> (r = t>>6, o = t&63) ---
    {
        const int r = t >> 6, oo = t & 63;
        float v = b_proj[oo];
#pragma unroll
        for (int c = 0; c < 16; ++c) v += part[r][c][oo];
        const int rowr = blockIdx.x * 4 + r;
        if (oo < 32) {
            Qbf[rowr * 32 + oo] = f2bf(v);     // q in bf16 (MFMA B operand)
        } else {
            k_sh[r][oo - 32] = v;              // k stays on-chip
        }
    }
    __syncthreads();

    // --- c0[row][p] = b_o[p] - sum_e k[row][e]*Wd[p][e]  (exact fp32) ---
    {
        const int p = t & 127;
        const int r0 = t >> 7;  // 0 or 1
#pragma unroll
        for (int rr = 0; rr < 2; ++rr) {
            const int r = r0 * 2 + rr;
            float a = 0.f;
#pragma unroll 8
            for (int e = 0; e < 32; ++e) a += k_sh[r][e] * Wdt[e * 128 + p];
            C0[(size_t)(blockIdx.x * 4 + r) * 128 + p] = b_o[p] - a;
        }
    }

    // --- Gall[row][p][e] = bf16(k[row][e]*Wp[p][e] + Wd[p][e]), rows of 32 shorts (64B) ---
    {
        const int p  = t >> 1;
        const int eh = (t & 1) * 16;
        const float* wp = Wo + p * 64 + eh;
        floatx4 wpc[4], wdc[4];
#pragma unroll
        for (int c = 0; c < 4; ++c) {
            wpc[c] = *(const floatx4*)(wp + c * 4);        // Wp[p][eh+4c .. +3]
            wdc[c] = *(const floatx4*)(wp + 32 + c * 4);   // Wd[p][eh+4c .. +3]
        }
#pragma unroll
        for (int r = 0; r < 4; ++r) {
            unsigned short g[16];
#pragma unroll
            for (int c = 0; c < 4; ++c) {
#pragma unroll
                for (int u = 0; u < 4; ++u) {
                    float kv = k_sh[r][eh + c * 4 + u];
                    g[c * 4 + u] = f2bf(kv * wpc[c][u] + wdc[c][u]);
                }
            }
            short8 lo, hi;
#pragma unroll
            for (int u = 0; u < 8; ++u) { lo[u] = (short)g[u]; hi[u] = (short)g[8 + u]; }
            unsigned short* gr = Gall + (size_t)(blockIdx.x * 4 + r) * 4096 + p * 32 + eh;
            *(short8*)(gr)     = lo;
            *(short8*)(gr + 8) = hi;
        }
    }
}

// ---------------- k2: pairwise GEMM, LDS-transpose epilogue, plain contiguous stores ----
// 1024 blocks x 256 threads, 4 blocks/CU. Per wave, per j-tile: 8 MFMA -> 8 rotated
// b128 LDS writes (wave-private 16x128 tile) -> 8 b128 reads -> 8 plain 1KB stores,
// ascending addresses. Wave writes a sequential 64KB stream; no barriers anywhere.
__global__ __launch_bounds__(256, 4) void k2_pair(
    const unsigned short* __restrict__ Qbf, const unsigned short* __restrict__ Gall,
    const float* __restrict__ C0, float* __restrict__ out)
{
    __shared__ __attribute__((aligned(16))) float T[4][16][132]; // per-wave [j16][p128+pad]

    const int t  = threadIdx.x;
    const int bi = blockIdx.x;        // b*512 + i
    const int b  = bi >> 9;
    const int wave = t >> 6, lane = t & 63;
    const int col = lane & 15, quad = lane >> 4;
    const int hi  = lane >> 5;        // store phase: row parity
    const int c8  = lane & 31;        // store phase: 16B chunk

    // A-operand (G^T): A[m][k] = G[pt*16+col][quad*8+u] -> contiguous 1KB wave-load per pt
    const unsigned short* gb = Gall + (size_t)bi * 4096 + (size_t)col * 32 + quad * 8;
    short8 gfrag[8];
#pragma unroll
    for (int pt = 0; pt < 8; ++pt)
        gfrag[pt] = *(const short8*)(gb + pt * 512);

    // C-in: c0[p] at p = pt*16 + quad*4 + r (r = acc reg index)
    floatx4 cv[8];
#pragma unroll
    for (int pt = 0; pt < 8; ++pt)
        cv[pt] = *(const floatx4*)(C0 + (size_t)bi * 128 + pt * 16 + quad * 4);

    // B-operand (Q): B[k][n] = Q[j0+col][quad*8+u] -> contiguous 1KB wave-load per j-tile
    const unsigned short* qp = Qbf + ((size_t)b * 512 + wave * 128 + col) * 32 + quad * 8;
    float* outw = out + (size_t)bi * (512 * 128) + (size_t)wave * (128 * 128);

    float (*Tw)[132] = T[wave];

    short8 a_cur = *(const short8*)qp;
#pragma unroll 1
    for (int l = 0; l < 8; ++l) {
        short8 a_nxt = a_cur;
        if (l < 7) a_nxt = *(const short8*)(qp + (size_t)(l + 1) * 512);

        // MFMA -> transpose write. Lane holds D[p = pt*16+quad*4+r][j = col].
        // Logical 16B chunk x = pt*4+quad of row j=col, placed rotated at (x+col)&31
        // so banks spread uniformly (row-major col-fast layout would be 8-way).
#pragma unroll
        for (int pt = 0; pt < 8; ++pt) {
            floatx4 acc = __builtin_amdgcn_mfma_f32_16x16x32_bf16(gfrag[pt], a_cur, cv[pt], 0, 0, 0);
            const int cz = (pt * 4 + quad + col) & 31;
            *(floatx4*)&Tw[col][cz * 4] = acc;
        }

        // Contiguous store: instr s covers rows {2s, 2s+1} completely (1KB, ascending).
        float* orow = outw + (size_t)l * (16 * 128);
#pragma unroll
        for (int s = 0; s < 8; ++s) {
            const int rr = s * 2 + hi;
            floatx4 v = *(const floatx4*)&Tw[rr][((c8 + rr) & 31) * 4]; // un-rotate
            *(floatx4*)(orow + rr * 128 + c8 * 4) = v;                  // plain store
        }
        a_cur = a_nxt;
    }
}

extern "C" void kernel_launch(void* const* d_in, const int* in_sizes, int n_in,
                              void* d_out, int out_size, void* d_ws, size_t ws_size,
                              hipStream_t stream) {
    const float* x     = (const float*)d_in[0];  // (2,512,1024)
    const float* gamma = (const float*)d_in[1];  // (1024)
    const float* beta  = (const float*)d_in[2];  // (1024)
    const float* Wproj = (const float*)d_in[3];  // (64,1024)
    const float* bproj = (const float*)d_in[4];  // (64)
    const float* Wo    = (const float*)d_in[5];  // (128,64)
    const float* bo    = (const float*)d_in[6];  // (128)
    float* out = (float*)d_out;                  // (2,512,512,128) fp32

    float* ws = (float*)d_ws;
    float* Wt  = ws;                    // 65536 floats (1024x64)
    float* Wdt = ws + 65536;            // 4096 floats  (32x128)
    float* C0  = ws + 69632;            // 131072 floats (1024x128)
    unsigned short* Qbf  = (unsigned short*)(ws + 200704); // 32768 ushorts (1024x32)
    unsigned short* Gall = (unsigned short*)(ws + 217088); // 4194304 ushorts (1024x128x32)

    hipLaunchKernelGGL(k0_transpose, dim3(272), dim3(256), 0, stream,
                       Wproj, Wo, Wt, Wdt);
    hipLaunchKernelGGL(k1_ln_proj, dim3(256), dim3(256), 0, stream,
                       x, gamma, beta, Wt, bproj, Wdt, bo, Wo, Qbf, C0, Gall);
    hipLaunchKernelGGL(k2_pair, dim3(1024), dim3(256), 0, stream,
                       Qbf, Gall, C0, out);
}